// Round 1
// baseline (228.194 us; speedup 1.0000x reference)
//
#include <hip/hip_runtime.h>

// VectorQuantizer on MI355X (gfx950) — round 3: LDS-resident codebook fragments
// x: [262144, 64] fp32; embeddings: [64, 512] fp32 (codes are COLUMNS)
// out: quantized [N*64] fp32 ++ loss scalar
//
// sim = x.e computed as xh.eh + xl.eh + xh.el (bf16 split, abs err ~3e-5)
// score = sim - 0.5*||e||^2  (accumulator-initialized; argmax == argmin dist)
// Round-3 changes vs round-2 (138 us, latency-bound, all pipes <30%):
//   1. Codebook MFMA fragments (eh 64KB + el 64KB) + scaled norms staged in LDS
//      once per 1024-thread block. Round-2 re-read them from global every
//      t-iteration (512 MB device-wide of a 128KB table) and the streaming
//      x/out traffic evicted them from L2 -> per-iteration L3 latency stall.
//   2. -0.5*cnorm folded into MFMA acc init: kills the per-candidate fma.
// near-tie (gap < 1e-3): whole-wave cooperative exact fp64 rescan (rare)

#define NVEC 262144
#define DDIM 64
#define KCB  512
#define TIE_TH 1e-3f

// ws layout (4-byte units)
#define WS_LOSS  0
#define WS_CNORM 64                      // 512 floats
#define WS_ET    1024                    // 512*64 floats (code-major codebook)
#define WS_EH    (WS_ET + KCB * DDIM)    // 32 tiles * 2 chunks * 64 lanes * 16B
#define WS_EL    (WS_EH + 32 * 2 * 64 * 4)
#define WS_END   (WS_EL + 32 * 2 * 64 * 4)

typedef __attribute__((ext_vector_type(8))) short bf16x8;
typedef __attribute__((ext_vector_type(4))) float f32x4;

static __device__ __forceinline__ unsigned short f2bf_rne(float f) {
    unsigned u = __float_as_uint(f);
    unsigned r = (u + 0x7FFFu + ((u >> 16) & 1u)) >> 16;
    return (unsigned short)r;
}
static __device__ __forceinline__ float bf2f(unsigned short h) {
    return __uint_as_float(((unsigned)h) << 16);
}

// ---------------- prep 1: et (code-major fp32), cnorm, zero loss ----------------
__global__ __launch_bounds__(512) void vq_prep1(const float* __restrict__ emb,
                                                float* __restrict__ wsf) {
    int k = threadIdx.x;
    float s = 0.f;
    float* et = wsf + WS_ET;
    #pragma unroll
    for (int d = 0; d < DDIM; ++d) {
        float e = emb[d * KCB + k];
        s += e * e;
        et[k * DDIM + d] = e;
    }
    wsf[WS_CNORM + k] = s;
    if (k == 0) wsf[WS_LOSS] = 0.f;
}

// ---------------- prep 2: codebook MFMA A-fragments (hi/lo bf16) ----------------
// frag index ((t*2+c)*64 + lane): 8 bf16 = A[m = t*16+(lane&15)][k = c*32+quad*8+j]
__global__ __launch_bounds__(512) void vq_prep2(const float* __restrict__ emb,
                                                float* __restrict__ wsf) {
    int tid = blockIdx.x * 512 + threadIdx.x;   // 0..4095
    if (tid >= 32 * 2 * 64) return;
    int l = tid & 63;
    int c = (tid >> 6) & 1;
    int t = tid >> 7;
    int m = t * 16 + (l & 15);
    int dbase = c * 32 + ((l >> 4) & 3) * 8;
    unsigned hh[4], ll[4];
    #pragma unroll
    for (int j2 = 0; j2 < 4; ++j2) {
        float f0 = emb[(dbase + 2 * j2 + 0) * KCB + m];
        float f1 = emb[(dbase + 2 * j2 + 1) * KCB + m];
        unsigned short h0 = f2bf_rne(f0), h1 = f2bf_rne(f1);
        unsigned short l0 = f2bf_rne(f0 - bf2f(h0)), l1 = f2bf_rne(f1 - bf2f(h1));
        hh[j2] = (unsigned)h0 | ((unsigned)h1 << 16);
        ll[j2] = (unsigned)l0 | ((unsigned)l1 << 16);
    }
    uint4* ehp = (uint4*)(wsf + WS_EH);
    uint4* elp = (uint4*)(wsf + WS_EL);
    ehp[tid] = make_uint4(hh[0], hh[1], hh[2], hh[3]);
    elp[tid] = make_uint4(ll[0], ll[1], ll[2], ll[3]);
}

// ---------------- main: 1024-thread block = 16 waves, codebook frags in LDS ----------------
// Each wave handles 64 vectors vs all 512 codes. LDS: eh 64KB + el 64KB + cn 2KB = 130KB
// -> exactly 1 block/CU (16 waves/CU, same residency as round-2, but frag reads are
// now ds_read_b128 lane-linear conflict-free instead of L3-latency global loads).
__global__ __launch_bounds__(1024, 4) void vq_main_mfma(const float* __restrict__ x,
                                                        const float* __restrict__ wsf,
                                                        float* __restrict__ out,
                                                        float* __restrict__ loss_accum) {
    const int lane = threadIdx.x & 63;
    const int quad = lane >> 4;
    const int nbase = (blockIdx.x * 16 + (threadIdx.x >> 6)) * 64;

    __shared__ uint4  sh_eh[32 * 2 * 64];   // 64 KB
    __shared__ uint4  sh_el[32 * 2 * 64];   // 64 KB
    __shared__ float4 sh_cn[128];           // 2 KB: -0.5 * ||e||^2

    // ---- stage codebook fragments + scaled norms into LDS (once per block) ----
    {
        const uint4* geh = (const uint4*)(wsf + WS_EH);
        const uint4* gel = (const uint4*)(wsf + WS_EL);
        const int tid = threadIdx.x;
        #pragma unroll
        for (int i = 0; i < 4; ++i) {
            sh_eh[tid + i * 1024] = geh[tid + i * 1024];
            sh_el[tid + i * 1024] = gel[tid + i * 1024];
        }
        if (tid < 128) {
            float4 c = ((const float4*)(wsf + WS_CNORM))[tid];
            sh_cn[tid] = make_float4(-0.5f * c.x, -0.5f * c.y,
                                     -0.5f * c.z, -0.5f * c.w);
        }
    }

    const float* __restrict__ et = wsf + WS_ET;

    // ---- load x tile, build B-fragments (hi/lo), accumulate ||x||^2 ----
    // (overlaps the LDS staging latency; barrier comes after)
    bf16x8 xh[4][2], xl[4][2];
    float xnorm[4];
    #pragma unroll
    for (int j = 0; j < 4; ++j) {
        float s = 0.f;
        #pragma unroll
        for (int c = 0; c < 2; ++c) {
            const float* xrow = x + (size_t)(nbase + j * 16 + (lane & 15)) * DDIM
                                  + c * 32 + quad * 8;
            float4 xa = *(const float4*)xrow;
            float4 xb = *(const float4*)(xrow + 4);
            s += xa.x * xa.x + xa.y * xa.y + xa.z * xa.z + xa.w * xa.w;
            s += xb.x * xb.x + xb.y * xb.y + xb.z * xb.z + xb.w * xb.w;
            float f[8] = {xa.x, xa.y, xa.z, xa.w, xb.x, xb.y, xb.z, xb.w};
            union { bf16x8 v; unsigned short u[8]; } H, L;
            #pragma unroll
            for (int e = 0; e < 8; ++e) {
                unsigned short h = f2bf_rne(f[e]);
                H.u[e] = h;
                L.u[e] = f2bf_rne(f[e] - bf2f(h));
            }
            xh[j][c] = H.v;
            xl[j][c] = L.v;
        }
        // sum partial ||x||^2 across the 4 quads (bits 4,5 of lane)
        s += __shfl_xor(s, 16);
        s += __shfl_xor(s, 32);
        xnorm[j] = s;
    }

    __syncthreads();

    const bf16x8* __restrict__ ehv = (const bf16x8*)sh_eh;
    const bf16x8* __restrict__ elv = (const bf16x8*)sh_el;

    // ---- argmax of score = sim - 0.5*||e||^2 over 32 code-tiles ----
    float best[4], second[4];
    int bestv[4];  // t*16 + reg  (full code = bestv + quad*4)
    #pragma unroll
    for (int j = 0; j < 4; ++j) { best[j] = -3.4e38f; second[j] = -3.4e38f; bestv[j] = 0; }

    for (int t = 0; t < 32; ++t) {
        bf16x8 eh0 = ehv[(t * 2 + 0) * 64 + lane];
        bf16x8 eh1 = ehv[(t * 2 + 1) * 64 + lane];
        bf16x8 el0 = elv[(t * 2 + 0) * 64 + lane];
        bf16x8 el1 = elv[(t * 2 + 1) * 64 + lane];
        float4 cn = sh_cn[t * 4 + quad];
        const int kb = t * 16;
        #pragma unroll
        for (int j = 0; j < 4; ++j) {
            f32x4 acc = {cn.x, cn.y, cn.z, cn.w};   // start at -0.5*||e||^2
            acc = __builtin_amdgcn_mfma_f32_16x16x32_bf16(eh0, xh[j][0], acc, 0, 0, 0);
            acc = __builtin_amdgcn_mfma_f32_16x16x32_bf16(eh1, xh[j][1], acc, 0, 0, 0);
            acc = __builtin_amdgcn_mfma_f32_16x16x32_bf16(el0, xh[j][0], acc, 0, 0, 0);
            acc = __builtin_amdgcn_mfma_f32_16x16x32_bf16(el1, xh[j][1], acc, 0, 0, 0);
            acc = __builtin_amdgcn_mfma_f32_16x16x32_bf16(eh0, xl[j][0], acc, 0, 0, 0);
            acc = __builtin_amdgcn_mfma_f32_16x16x32_bf16(eh1, xl[j][1], acc, 0, 0, 0);
            #pragma unroll
            for (int r = 0; r < 4; ++r) {
                float s = acc[r];
                bool gt = s > best[j];
                second[j] = fmaxf(second[j], fminf(s, best[j]));
                bestv[j] = gt ? (kb + r) : bestv[j];
                best[j] = fmaxf(best[j], s);
            }
        }
    }

    // ---- reduce across the 4 quads (lanes n, n+16, n+32, n+48) ----
    int bk[4];
    #pragma unroll
    for (int j = 0; j < 4; ++j) bk[j] = bestv[j] + quad * 4;
    #pragma unroll
    for (int j = 0; j < 4; ++j) {
        #pragma unroll
        for (int m = 16; m <= 32; m <<= 1) {
            float ob = __shfl_xor(best[j], m);
            float os = __shfl_xor(second[j], m);
            int   ok = __shfl_xor(bk[j], m);
            float nb = fmaxf(best[j], ob);
            float ns = fmaxf(fmaxf(second[j], os), fminf(best[j], ob));
            bool take = (ob > best[j]) || (ob == best[j] && ok < bk[j]);
            bk[j] = take ? ok : bk[j];
            best[j] = nb;
            second[j] = ns;
        }
    }

    // ---- back to distance domain: dist = -2*score  (||x||^2 dropped) ----
    float bd[4], sd[4];
    #pragma unroll
    for (int j = 0; j < 4; ++j) { bd[j] = -2.f * best[j]; sd[j] = -2.f * second[j]; }

    // ---- near-tie: whole-wave cooperative exact fp64 rescan (rare) ----
    #pragma unroll
    for (int j = 0; j < 4; ++j) {
        unsigned long long need = __ballot(sd[j] - bd[j] < TIE_TH) & 0xFFFFULL;
        while (need) {
            int nl = __ffsll(need) - 1;
            need &= need - 1;
            const float* xr = x + (size_t)(nbase + j * 16 + nl) * DDIM;
            double dmin = 1e300;
            int kmin = 0;
            #pragma unroll
            for (int i = 0; i < 8; ++i) {
                int k = lane * 8 + i;
                const float* er = et + k * DDIM;
                double s = 0.0;
                for (int d4 = 0; d4 < 16; ++d4) {
                    float4 xv = *(const float4*)(xr + d4 * 4);
                    float4 ev = *(const float4*)(er + d4 * 4);
                    double a = (double)xv.x - (double)ev.x; s += a * a;
                    double b = (double)xv.y - (double)ev.y; s += b * b;
                    double c = (double)xv.z - (double)ev.z; s += c * c;
                    double e = (double)xv.w - (double)ev.w; s += e * e;
                }
                if (s < dmin) { dmin = s; kmin = k; }
            }
            #pragma unroll
            for (int m = 1; m < 64; m <<= 1) {
                double od = __shfl_xor(dmin, m);
                int   ok = __shfl_xor(kmin, m);
                if (od < dmin || (od == dmin && ok < kmin)) { dmin = od; kmin = ok; }
            }
            if ((lane & 15) == nl) {
                bk[j] = kmin;
                bd[j] = (float)dmin - xnorm[j];  // keep loss exact
            }
        }
    }

    // ---- loss partial: sum (q-x)^2 = xnorm + bd over this wave's 64 n ----
    float ls = 0.f;
    if (lane < 16) {
        #pragma unroll
        for (int j = 0; j < 4; ++j) ls += fmaxf(xnorm[j] + bd[j], 0.f);
    }
    #pragma unroll
    for (int m = 1; m < 64; m <<= 1) ls += __shfl_xor(ls, m);
    if (lane == 0) atomicAdd(loss_accum, ls);

    // ---- write quantized rows: lane -> (n = lane>>2, 64B slice = lane&3) ----
    #pragma unroll
    for (int j = 0; j < 4; ++j) {
        int bkn = __shfl(bk[j], lane >> 2);
        const float4* er = (const float4*)(et + (size_t)bkn * DDIM + (lane & 3) * 16);
        float4* op = (float4*)(out + (size_t)(nbase + j * 16 + (lane >> 2)) * DDIM
                                   + (lane & 3) * 16);
        op[0] = er[0]; op[1] = er[1]; op[2] = er[2]; op[3] = er[3];
    }
}

// ---------------- legacy fallback (round-1 kernel) if ws is too small ----------------
__global__ __launch_bounds__(256) void vq_main_legacy(const float* __restrict__ x,
                                                      const float* __restrict__ emb,
                                                      const float* __restrict__ wsf,
                                                      float* __restrict__ out,
                                                      float* __restrict__ loss_accum) {
    const int n = blockIdx.x * 256 + threadIdx.x;
    const float* __restrict__ cnorm = wsf + WS_CNORM;
    const float* __restrict__ et    = wsf + WS_ET;
    float xr[DDIM];
    {
        const float4* xp = (const float4*)(x + (size_t)n * DDIM);
        #pragma unroll
        for (int d4 = 0; d4 < DDIM / 4; ++d4) {
            float4 v = xp[d4];
            xr[4 * d4 + 0] = v.x; xr[4 * d4 + 1] = v.y;
            xr[4 * d4 + 2] = v.z; xr[4 * d4 + 3] = v.w;
        }
    }
    float best = 3.4e38f, second = 3.4e38f;
    int bestk = 0;
    for (int k0 = 0; k0 < KCB; k0 += 8) {
        float acc[8];
        #pragma unroll
        for (int j = 0; j < 8; ++j) acc[j] = 0.f;
        #pragma unroll
        for (int j = 0; j < 8; ++j) {
            const float* ek = et + (k0 + j) * DDIM;
            float s = 0.f;
            #pragma unroll
            for (int d = 0; d < DDIM; ++d) s += xr[d] * ek[d];
            acc[j] = s;
        }
        #pragma unroll
        for (int j = 0; j < 8; ++j) {
            float dist = cnorm[k0 + j] - 2.f * acc[j];
            if (dist < best) { second = best; best = dist; bestk = k0 + j; }
            else if (dist < second) { second = dist; }
        }
    }
    if (second - best < TIE_TH) {
        double bestd = 1e300;
        int bkk = 0;
        for (int k = 0; k < KCB; ++k) {
            const float* ek = et + k * DDIM;
            double s = 0.0;
            #pragma unroll
            for (int d = 0; d < DDIM; ++d) {
                double diff = (double)xr[d] - (double)ek[d];
                s += diff * diff;
            }
            if (s < bestd) { bestd = s; bkk = k; }
        }
        bestk = bkk;
    }
    float sq = 0.f;
    {
        const float4* qp = (const float4*)(et + bestk * DDIM);
        float4* op = (float4*)(out + (size_t)n * DDIM);
        #pragma unroll
        for (int d4 = 0; d4 < DDIM / 4; ++d4) {
            float4 q = qp[d4];
            op[d4] = q;
            float a = q.x - xr[4 * d4 + 0];
            float b = q.y - xr[4 * d4 + 1];
            float c = q.z - xr[4 * d4 + 2];
            float e = q.w - xr[4 * d4 + 3];
            sq += a * a + b * b + c * c + e * e;
        }
    }
    #pragma unroll
    for (int off = 32; off > 0; off >>= 1) sq += __shfl_down(sq, off);
    __shared__ float red[4];
    const int lane = threadIdx.x & 63;
    const int wid  = threadIdx.x >> 6;
    if (lane == 0) red[wid] = sq;
    __syncthreads();
    if (threadIdx.x == 0) atomicAdd(loss_accum, red[0] + red[1] + red[2] + red[3]);
}

__global__ void vq_final(const float* __restrict__ loss_accum,
                         float* __restrict__ out) {
    out[(size_t)NVEC * DDIM] = 1.25f * loss_accum[0] / 16777216.f;
}

extern "C" void kernel_launch(void* const* d_in, const int* in_sizes, int n_in,
                              void* d_out, int out_size, void* d_ws, size_t ws_size,
                              hipStream_t stream) {
    const float* x   = (const float*)d_in[0];
    const float* emb = (const float*)d_in[1];
    float* out = (float*)d_out;
    float* wsf = (float*)d_ws;

    vq_prep1<<<1, 512, 0, stream>>>(emb, wsf);
    if (ws_size >= (size_t)WS_END * 4) {
        vq_prep2<<<8, 512, 0, stream>>>(emb, wsf);
        vq_main_mfma<<<NVEC / 1024, 1024, 0, stream>>>(x, wsf, out, wsf + WS_LOSS);
    } else {
        vq_main_legacy<<<NVEC / 256, 256, 0, stream>>>(x, emb, wsf, out, wsf + WS_LOSS);
    }
    vq_final<<<1, 1, 0, stream>>>(wsf + WS_LOSS, out);
}

// Round 2
// 210.599 us; speedup vs baseline: 1.0835x; 1.0835x over previous
//
#include <hip/hip_runtime.h>

// VectorQuantizer on MI355X (gfx950) — round 4: kill the scratch spill
// x: [262144, 64] fp32; embeddings: [64, 512] fp32 (codes are COLUMNS)
// out: quantized [N*64] fp32 ++ loss scalar
//
// sim = x.e computed as xh.eh + xl.eh + xh.el (bf16 split, abs err ~3e-5)
// score = sim - 0.5*||e||^2  (accumulator-initialized; argmax == argmin dist)
//
// Round-4 changes vs round-3 (131 us, latency-bound, VGPR=64 forced by
// launch_bounds(1024,4) -> x-fragments spilled to scratch: WRITE_SIZE was
// 116 MB vs 64 MB of real output, FETCH up 25 MB; scratch reloads inside the
// t-loop were the stall):
//   1. j=4 -> j=2: each wave owns 32 rows (live set ~90 VGPR, fits the 128-reg
//      ceiling a 16-wave block imposes). Block runs 2 passes over consecutive
//      512-vector super-tiles; LDS table staged once per block.
//   2. __launch_bounds__(1024) only — no min-waves arg, so the compiler is
//      free to use up to 128 VGPRs (block residency still guaranteed).
//   3. Manual prefetch of next t-tile's LDS fragments (hide ds_read latency).
//   4. second-best update via v_med3_f32 (1 op instead of 2 per candidate).
// near-tie (gap < 1e-3): whole-wave cooperative exact fp64 rescan (rare)

#define NVEC 262144
#define DDIM 64
#define KCB  512
#define TIE_TH 1e-3f

// ws layout (4-byte units)
#define WS_LOSS  0
#define WS_CNORM 64                      // 512 floats
#define WS_ET    1024                    // 512*64 floats (code-major codebook)
#define WS_EH    (WS_ET + KCB * DDIM)    // 32 tiles * 2 chunks * 64 lanes * 16B
#define WS_EL    (WS_EH + 32 * 2 * 64 * 4)
#define WS_END   (WS_EL + 32 * 2 * 64 * 4)

typedef __attribute__((ext_vector_type(8))) short bf16x8;
typedef __attribute__((ext_vector_type(4))) float f32x4;

static __device__ __forceinline__ unsigned short f2bf_rne(float f) {
    unsigned u = __float_as_uint(f);
    unsigned r = (u + 0x7FFFu + ((u >> 16) & 1u)) >> 16;
    return (unsigned short)r;
}
static __device__ __forceinline__ float bf2f(unsigned short h) {
    return __uint_as_float(((unsigned)h) << 16);
}

// ---------------- prep 1: et (code-major fp32), cnorm, zero loss ----------------
__global__ __launch_bounds__(512) void vq_prep1(const float* __restrict__ emb,
                                                float* __restrict__ wsf) {
    int k = threadIdx.x;
    float s = 0.f;
    float* et = wsf + WS_ET;
    #pragma unroll
    for (int d = 0; d < DDIM; ++d) {
        float e = emb[d * KCB + k];
        s += e * e;
        et[k * DDIM + d] = e;
    }
    wsf[WS_CNORM + k] = s;
    if (k == 0) wsf[WS_LOSS] = 0.f;
}

// ---------------- prep 2: codebook MFMA A-fragments (hi/lo bf16) ----------------
// frag index ((t*2+c)*64 + lane): 8 bf16 = A[m = t*16+(lane&15)][k = c*32+quad*8+j]
__global__ __launch_bounds__(512) void vq_prep2(const float* __restrict__ emb,
                                                float* __restrict__ wsf) {
    int tid = blockIdx.x * 512 + threadIdx.x;   // 0..4095
    if (tid >= 32 * 2 * 64) return;
    int l = tid & 63;
    int c = (tid >> 6) & 1;
    int t = tid >> 7;
    int m = t * 16 + (l & 15);
    int dbase = c * 32 + ((l >> 4) & 3) * 8;
    unsigned hh[4], ll[4];
    #pragma unroll
    for (int j2 = 0; j2 < 4; ++j2) {
        float f0 = emb[(dbase + 2 * j2 + 0) * KCB + m];
        float f1 = emb[(dbase + 2 * j2 + 1) * KCB + m];
        unsigned short h0 = f2bf_rne(f0), h1 = f2bf_rne(f1);
        unsigned short l0 = f2bf_rne(f0 - bf2f(h0)), l1 = f2bf_rne(f1 - bf2f(h1));
        hh[j2] = (unsigned)h0 | ((unsigned)h1 << 16);
        ll[j2] = (unsigned)l0 | ((unsigned)l1 << 16);
    }
    uint4* ehp = (uint4*)(wsf + WS_EH);
    uint4* elp = (uint4*)(wsf + WS_EL);
    ehp[tid] = make_uint4(hh[0], hh[1], hh[2], hh[3]);
    elp[tid] = make_uint4(ll[0], ll[1], ll[2], ll[3]);
}

// ---------------- main: 1024-thread block = 16 waves, table in LDS, 2 passes ----------------
// Each wave handles 32 vectors/pass vs all 512 codes; 2 passes/block.
// LDS: eh 64KB + el 64KB + cn 2KB = 130KB -> 1 block/CU, 16 waves resident.
// VGPR budget: 16-wave block caps at 128 regs/wave; j=2 live set ~90 -> no spill.
__global__ __launch_bounds__(1024) void vq_main_mfma(const float* __restrict__ x,
                                                     const float* __restrict__ wsf,
                                                     float* __restrict__ out,
                                                     float* __restrict__ loss_accum) {
    const int lane = threadIdx.x & 63;
    const int quad = lane >> 4;
    const int wid  = threadIdx.x >> 6;

    __shared__ uint4  sh_eh[32 * 2 * 64];   // 64 KB
    __shared__ uint4  sh_el[32 * 2 * 64];   // 64 KB
    __shared__ float4 sh_cn[128];           // 2 KB: -0.5 * ||e||^2

    // ---- stage codebook fragments + scaled norms into LDS (once per block) ----
    {
        const uint4* geh = (const uint4*)(wsf + WS_EH);
        const uint4* gel = (const uint4*)(wsf + WS_EL);
        const int tid = threadIdx.x;
        #pragma unroll
        for (int i = 0; i < 4; ++i) {
            sh_eh[tid + i * 1024] = geh[tid + i * 1024];
            sh_el[tid + i * 1024] = gel[tid + i * 1024];
        }
        if (tid < 128) {
            float4 c = ((const float4*)(wsf + WS_CNORM))[tid];
            sh_cn[tid] = make_float4(-0.5f * c.x, -0.5f * c.y,
                                     -0.5f * c.z, -0.5f * c.w);
        }
    }
    __syncthreads();

    const float* __restrict__ et = wsf + WS_ET;
    const bf16x8* __restrict__ ehv = (const bf16x8*)sh_eh;
    const bf16x8* __restrict__ elv = (const bf16x8*)sh_el;

    float loss_ws = 0.f;

    #pragma unroll 1
    for (int pass = 0; pass < 2; ++pass) {
        const int nbase = (blockIdx.x * 2 + pass) * 512 + wid * 32;

        // ---- load 32 x rows, build B-fragments (hi/lo), accumulate ||x||^2 ----
        bf16x8 xh[2][2], xl[2][2];
        float xnorm[2];
        #pragma unroll
        for (int j = 0; j < 2; ++j) {
            float s = 0.f;
            #pragma unroll
            for (int c = 0; c < 2; ++c) {
                const float* xrow = x + (size_t)(nbase + j * 16 + (lane & 15)) * DDIM
                                      + c * 32 + quad * 8;
                float4 xa = *(const float4*)xrow;
                float4 xb = *(const float4*)(xrow + 4);
                s += xa.x * xa.x + xa.y * xa.y + xa.z * xa.z + xa.w * xa.w;
                s += xb.x * xb.x + xb.y * xb.y + xb.z * xb.z + xb.w * xb.w;
                float f[8] = {xa.x, xa.y, xa.z, xa.w, xb.x, xb.y, xb.z, xb.w};
                union { bf16x8 v; unsigned short u[8]; } H, L;
                #pragma unroll
                for (int e = 0; e < 8; ++e) {
                    unsigned short h = f2bf_rne(f[e]);
                    H.u[e] = h;
                    L.u[e] = f2bf_rne(f[e] - bf2f(h));
                }
                xh[j][c] = H.v;
                xl[j][c] = L.v;
            }
            // sum partial ||x||^2 across the 4 quads (bits 4,5 of lane)
            s += __shfl_xor(s, 16);
            s += __shfl_xor(s, 32);
            xnorm[j] = s;
        }

        // ---- argmax of score = sim - 0.5*||e||^2 over 32 code-tiles ----
        float best[2], second[2];
        int bestv[2];  // t*16 + reg  (full code = bestv + quad*4)
        #pragma unroll
        for (int j = 0; j < 2; ++j) { best[j] = -3.4e38f; second[j] = -3.4e38f; bestv[j] = 0; }

        // prefetched fragments for tile t
        bf16x8 eh0 = ehv[lane], eh1 = ehv[64 + lane];
        bf16x8 el0 = elv[lane], el1 = elv[64 + lane];

        #pragma unroll 1
        for (int t = 0; t < 32; ++t) {
            // prefetch t+1 (wraps to t=0 on last iter; harmless, unused)
            const int tn = (t + 1) & 31;
            bf16x8 neh0 = ehv[(tn * 2 + 0) * 64 + lane];
            bf16x8 neh1 = ehv[(tn * 2 + 1) * 64 + lane];
            bf16x8 nel0 = elv[(tn * 2 + 0) * 64 + lane];
            bf16x8 nel1 = elv[(tn * 2 + 1) * 64 + lane];
            float4 cn = sh_cn[t * 4 + quad];
            const int kb = t * 16;
            #pragma unroll
            for (int j = 0; j < 2; ++j) {
                f32x4 acc = {cn.x, cn.y, cn.z, cn.w};   // start at -0.5*||e||^2
                acc = __builtin_amdgcn_mfma_f32_16x16x32_bf16(eh0, xh[j][0], acc, 0, 0, 0);
                acc = __builtin_amdgcn_mfma_f32_16x16x32_bf16(eh1, xh[j][1], acc, 0, 0, 0);
                acc = __builtin_amdgcn_mfma_f32_16x16x32_bf16(el0, xh[j][0], acc, 0, 0, 0);
                acc = __builtin_amdgcn_mfma_f32_16x16x32_bf16(el1, xh[j][1], acc, 0, 0, 0);
                acc = __builtin_amdgcn_mfma_f32_16x16x32_bf16(eh0, xl[j][0], acc, 0, 0, 0);
                acc = __builtin_amdgcn_mfma_f32_16x16x32_bf16(eh1, xl[j][1], acc, 0, 0, 0);
                #pragma unroll
                for (int r = 0; r < 4; ++r) {
                    float s = acc[r];
                    // new second = median(s, best, second) given best >= second
                    second[j] = __builtin_amdgcn_fmed3f(s, best[j], second[j]);
                    bool gt = s > best[j];
                    bestv[j] = gt ? (kb + r) : bestv[j];
                    best[j] = fmaxf(best[j], s);
                }
            }
            eh0 = neh0; eh1 = neh1; el0 = nel0; el1 = nel1;
        }

        // ---- reduce across the 4 quads (lanes n, n+16, n+32, n+48) ----
        int bk[2];
        #pragma unroll
        for (int j = 0; j < 2; ++j) bk[j] = bestv[j] + quad * 4;
        #pragma unroll
        for (int j = 0; j < 2; ++j) {
            #pragma unroll
            for (int m = 16; m <= 32; m <<= 1) {
                float ob = __shfl_xor(best[j], m);
                float os = __shfl_xor(second[j], m);
                int   ok = __shfl_xor(bk[j], m);
                float nb = fmaxf(best[j], ob);
                float ns = fmaxf(fmaxf(second[j], os), fminf(best[j], ob));
                bool take = (ob > best[j]) || (ob == best[j] && ok < bk[j]);
                bk[j] = take ? ok : bk[j];
                best[j] = nb;
                second[j] = ns;
            }
        }

        // ---- back to distance domain: dist = -2*score  (||x||^2 dropped) ----
        float bd[2], sd[2];
        #pragma unroll
        for (int j = 0; j < 2; ++j) { bd[j] = -2.f * best[j]; sd[j] = -2.f * second[j]; }

        // ---- near-tie: whole-wave cooperative exact fp64 rescan (rare) ----
        #pragma unroll
        for (int j = 0; j < 2; ++j) {
            unsigned long long need = __ballot(sd[j] - bd[j] < TIE_TH) & 0xFFFFULL;
            while (need) {
                int nl = __ffsll(need) - 1;
                need &= need - 1;
                const float* xr = x + (size_t)(nbase + j * 16 + nl) * DDIM;
                double dmin = 1e300;
                int kmin = 0;
                #pragma unroll
                for (int i = 0; i < 8; ++i) {
                    int k = lane * 8 + i;
                    const float* er = et + k * DDIM;
                    double s = 0.0;
                    for (int d4 = 0; d4 < 16; ++d4) {
                        float4 xv = *(const float4*)(xr + d4 * 4);
                        float4 ev = *(const float4*)(er + d4 * 4);
                        double a = (double)xv.x - (double)ev.x; s += a * a;
                        double b = (double)xv.y - (double)ev.y; s += b * b;
                        double c = (double)xv.z - (double)ev.z; s += c * c;
                        double e = (double)xv.w - (double)ev.w; s += e * e;
                    }
                    if (s < dmin) { dmin = s; kmin = k; }
                }
                #pragma unroll
                for (int m = 1; m < 64; m <<= 1) {
                    double od = __shfl_xor(dmin, m);
                    int   ok = __shfl_xor(kmin, m);
                    if (od < dmin || (od == dmin && ok < kmin)) { dmin = od; kmin = ok; }
                }
                if ((lane & 15) == nl) {
                    bk[j] = kmin;
                    bd[j] = (float)dmin - xnorm[j];  // keep loss exact
                }
            }
        }

        // ---- loss partial: sum (q-x)^2 = xnorm + bd over this wave's 32 n ----
        float ls = 0.f;
        if (lane < 16) {
            #pragma unroll
            for (int j = 0; j < 2; ++j) ls += fmaxf(xnorm[j] + bd[j], 0.f);
        }
        #pragma unroll
        for (int m = 1; m < 64; m <<= 1) ls += __shfl_xor(ls, m);
        loss_ws += ls;

        // ---- write quantized rows: lane -> (n = lane>>2, 64B slice = lane&3) ----
        #pragma unroll
        for (int j = 0; j < 2; ++j) {
            int bkn = __shfl(bk[j], lane >> 2);
            const float4* er = (const float4*)(et + (size_t)bkn * DDIM + (lane & 3) * 16);
            float4* op = (float4*)(out + (size_t)(nbase + j * 16 + (lane >> 2)) * DDIM
                                       + (lane & 3) * 16);
            op[0] = er[0]; op[1] = er[1]; op[2] = er[2]; op[3] = er[3];
        }
    }

    if (lane == 0) atomicAdd(loss_accum, loss_ws);
}

// ---------------- legacy fallback (round-1 kernel) if ws is too small ----------------
__global__ __launch_bounds__(256) void vq_main_legacy(const float* __restrict__ x,
                                                      const float* __restrict__ emb,
                                                      const float* __restrict__ wsf,
                                                      float* __restrict__ out,
                                                      float* __restrict__ loss_accum) {
    const int n = blockIdx.x * 256 + threadIdx.x;
    const float* __restrict__ cnorm = wsf + WS_CNORM;
    const float* __restrict__ et    = wsf + WS_ET;
    float xr[DDIM];
    {
        const float4* xp = (const float4*)(x + (size_t)n * DDIM);
        #pragma unroll
        for (int d4 = 0; d4 < DDIM / 4; ++d4) {
            float4 v = xp[d4];
            xr[4 * d4 + 0] = v.x; xr[4 * d4 + 1] = v.y;
            xr[4 * d4 + 2] = v.z; xr[4 * d4 + 3] = v.w;
        }
    }
    float best = 3.4e38f, second = 3.4e38f;
    int bestk = 0;
    for (int k0 = 0; k0 < KCB; k0 += 8) {
        float acc[8];
        #pragma unroll
        for (int j = 0; j < 8; ++j) acc[j] = 0.f;
        #pragma unroll
        for (int j = 0; j < 8; ++j) {
            const float* ek = et + (k0 + j) * DDIM;
            float s = 0.f;
            #pragma unroll
            for (int d = 0; d < DDIM; ++d) s += xr[d] * ek[d];
            acc[j] = s;
        }
        #pragma unroll
        for (int j = 0; j < 8; ++j) {
            float dist = cnorm[k0 + j] - 2.f * acc[j];
            if (dist < best) { second = best; best = dist; bestk = k0 + j; }
            else if (dist < second) { second = dist; }
        }
    }
    if (second - best < TIE_TH) {
        double bestd = 1e300;
        int bkk = 0;
        for (int k = 0; k < KCB; ++k) {
            const float* ek = et + k * DDIM;
            double s = 0.0;
            #pragma unroll
            for (int d = 0; d < DDIM; ++d) {
                double diff = (double)xr[d] - (double)ek[d];
                s += diff * diff;
            }
            if (s < bestd) { bestd = s; bkk = k; }
        }
        bestk = bkk;
    }
    float sq = 0.f;
    {
        const float4* qp = (const float4*)(et + bestk * DDIM);
        float4* op = (float4*)(out + (size_t)n * DDIM);
        #pragma unroll
        for (int d4 = 0; d4 < DDIM / 4; ++d4) {
            float4 q = qp[d4];
            op[d4] = q;
            float a = q.x - xr[4 * d4 + 0];
            float b = q.y - xr[4 * d4 + 1];
            float c = q.z - xr[4 * d4 + 2];
            float e = q.w - xr[4 * d4 + 3];
            sq += a * a + b * b + c * c + e * e;
        }
    }
    #pragma unroll
    for (int off = 32; off > 0; off >>= 1) sq += __shfl_down(sq, off);
    __shared__ float red[4];
    const int lane = threadIdx.x & 63;
    const int wid  = threadIdx.x >> 6;
    if (lane == 0) red[wid] = sq;
    __syncthreads();
    if (threadIdx.x == 0) atomicAdd(loss_accum, red[0] + red[1] + red[2] + red[3]);
}

__global__ void vq_final(const float* __restrict__ loss_accum,
                         float* __restrict__ out) {
    out[(size_t)NVEC * DDIM] = 1.25f * loss_accum[0] / 16777216.f;
}

extern "C" void kernel_launch(void* const* d_in, const int* in_sizes, int n_in,
                              void* d_out, int out_size, void* d_ws, size_t ws_size,
                              hipStream_t stream) {
    const float* x   = (const float*)d_in[0];
    const float* emb = (const float*)d_in[1];
    float* out = (float*)d_out;
    float* wsf = (float*)d_ws;

    vq_prep1<<<1, 512, 0, stream>>>(emb, wsf);
    if (ws_size >= (size_t)WS_END * 4) {
        vq_prep2<<<8, 512, 0, stream>>>(emb, wsf);
        vq_main_mfma<<<NVEC / 1024, 1024, 0, stream>>>(x, wsf, out, wsf + WS_LOSS);
    } else {
        vq_main_legacy<<<NVEC / 256, 256, 0, stream>>>(x, emb, wsf, out, wsf + WS_LOSS);
    }
    vq_final<<<1, 1, 0, stream>>>(wsf + WS_LOSS, out);
}

// Round 3
// 209.116 us; speedup vs baseline: 1.0912x; 1.0071x over previous
//
#include <hip/hip_runtime.h>

// VectorQuantizer on MI355X (gfx950) — round 5: lift the VGPR cap to 128
// x: [262144, 64] fp32; embeddings: [64, 512] fp32 (codes are COLUMNS)
// out: quantized [N*64] fp32 ++ loss scalar
//
// sim = x.e computed as xh.eh + xl.eh + xh.el (bf16 split, abs err ~3e-5)
// score = sim - 0.5*||e||^2  (accumulator-initialized; argmax == argmin dist)
//
// Round-5 change vs round-4 (115 us): compiler still chose VGPR=64 (heuristic
// targets 8 waves/EU, ignoring that the 130 KB LDS table already pins the
// block to 1/CU = 4 waves/EU). Live set ~100 regs -> ~12 regs/thread spilled
// (WRITE_SIZE 79 MB vs 67 MB real output), reloaded inside the t-loop = the
// remaining latency stall. Fix: __attribute__((amdgpu_waves_per_eu(4,4)))
// declares the truth -> legal cap 512/4 = 128 VGPRs -> no spill.
// near-tie (gap < 1e-3): whole-wave cooperative exact fp64 rescan (rare)

#define NVEC 262144
#define DDIM 64
#define KCB  512
#define TIE_TH 1e-3f

// ws layout (4-byte units)
#define WS_LOSS  0
#define WS_CNORM 64                      // 512 floats
#define WS_ET    1024                    // 512*64 floats (code-major codebook)
#define WS_EH    (WS_ET + KCB * DDIM)    // 32 tiles * 2 chunks * 64 lanes * 16B
#define WS_EL    (WS_EH + 32 * 2 * 64 * 4)
#define WS_END   (WS_EL + 32 * 2 * 64 * 4)

typedef __attribute__((ext_vector_type(8))) short bf16x8;
typedef __attribute__((ext_vector_type(4))) float f32x4;

static __device__ __forceinline__ unsigned short f2bf_rne(float f) {
    unsigned u = __float_as_uint(f);
    unsigned r = (u + 0x7FFFu + ((u >> 16) & 1u)) >> 16;
    return (unsigned short)r;
}
static __device__ __forceinline__ float bf2f(unsigned short h) {
    return __uint_as_float(((unsigned)h) << 16);
}

// ---------------- prep 1: et (code-major fp32), cnorm, zero loss ----------------
__global__ __launch_bounds__(512) void vq_prep1(const float* __restrict__ emb,
                                                float* __restrict__ wsf) {
    int k = threadIdx.x;
    float s = 0.f;
    float* et = wsf + WS_ET;
    #pragma unroll
    for (int d = 0; d < DDIM; ++d) {
        float e = emb[d * KCB + k];
        s += e * e;
        et[k * DDIM + d] = e;
    }
    wsf[WS_CNORM + k] = s;
    if (k == 0) wsf[WS_LOSS] = 0.f;
}

// ---------------- prep 2: codebook MFMA A-fragments (hi/lo bf16) ----------------
// frag index ((t*2+c)*64 + lane): 8 bf16 = A[m = t*16+(lane&15)][k = c*32+quad*8+j]
__global__ __launch_bounds__(512) void vq_prep2(const float* __restrict__ emb,
                                                float* __restrict__ wsf) {
    int tid = blockIdx.x * 512 + threadIdx.x;   // 0..4095
    if (tid >= 32 * 2 * 64) return;
    int l = tid & 63;
    int c = (tid >> 6) & 1;
    int t = tid >> 7;
    int m = t * 16 + (l & 15);
    int dbase = c * 32 + ((l >> 4) & 3) * 8;
    unsigned hh[4], ll[4];
    #pragma unroll
    for (int j2 = 0; j2 < 4; ++j2) {
        float f0 = emb[(dbase + 2 * j2 + 0) * KCB + m];
        float f1 = emb[(dbase + 2 * j2 + 1) * KCB + m];
        unsigned short h0 = f2bf_rne(f0), h1 = f2bf_rne(f1);
        unsigned short l0 = f2bf_rne(f0 - bf2f(h0)), l1 = f2bf_rne(f1 - bf2f(h1));
        hh[j2] = (unsigned)h0 | ((unsigned)h1 << 16);
        ll[j2] = (unsigned)l0 | ((unsigned)l1 << 16);
    }
    uint4* ehp = (uint4*)(wsf + WS_EH);
    uint4* elp = (uint4*)(wsf + WS_EL);
    ehp[tid] = make_uint4(hh[0], hh[1], hh[2], hh[3]);
    elp[tid] = make_uint4(ll[0], ll[1], ll[2], ll[3]);
}

// ---------------- main: 1024-thread block = 16 waves, table in LDS, 2 passes ----------------
// Each wave handles 32 vectors/pass vs all 512 codes; 2 passes/block.
// LDS: eh 64KB + el 64KB + cn 2KB = 130KB -> 1 block/CU, 16 waves resident.
// amdgpu_waves_per_eu(4,4): LDS pins us at 4 waves/EU anyway -> VGPR cap 128,
// live set ~100 fits, no scratch.
__global__ __launch_bounds__(1024)
__attribute__((amdgpu_waves_per_eu(4, 4)))
void vq_main_mfma(const float* __restrict__ x,
                  const float* __restrict__ wsf,
                  float* __restrict__ out,
                  float* __restrict__ loss_accum) {
    const int lane = threadIdx.x & 63;
    const int quad = lane >> 4;
    const int wid  = threadIdx.x >> 6;

    __shared__ uint4  sh_eh[32 * 2 * 64];   // 64 KB
    __shared__ uint4  sh_el[32 * 2 * 64];   // 64 KB
    __shared__ float4 sh_cn[128];           // 2 KB: -0.5 * ||e||^2

    // ---- stage codebook fragments + scaled norms into LDS (once per block) ----
    {
        const uint4* geh = (const uint4*)(wsf + WS_EH);
        const uint4* gel = (const uint4*)(wsf + WS_EL);
        const int tid = threadIdx.x;
        #pragma unroll
        for (int i = 0; i < 4; ++i) {
            sh_eh[tid + i * 1024] = geh[tid + i * 1024];
            sh_el[tid + i * 1024] = gel[tid + i * 1024];
        }
        if (tid < 128) {
            float4 c = ((const float4*)(wsf + WS_CNORM))[tid];
            sh_cn[tid] = make_float4(-0.5f * c.x, -0.5f * c.y,
                                     -0.5f * c.z, -0.5f * c.w);
        }
    }
    __syncthreads();

    const float* __restrict__ et = wsf + WS_ET;
    const bf16x8* __restrict__ ehv = (const bf16x8*)sh_eh;
    const bf16x8* __restrict__ elv = (const bf16x8*)sh_el;

    float loss_ws = 0.f;

    #pragma unroll 1
    for (int pass = 0; pass < 2; ++pass) {
        const int nbase = (blockIdx.x * 2 + pass) * 512 + wid * 32;

        // ---- load 32 x rows, build B-fragments (hi/lo), accumulate ||x||^2 ----
        bf16x8 xh[2][2], xl[2][2];
        float xnorm[2];
        #pragma unroll
        for (int j = 0; j < 2; ++j) {
            float s = 0.f;
            #pragma unroll
            for (int c = 0; c < 2; ++c) {
                const float* xrow = x + (size_t)(nbase + j * 16 + (lane & 15)) * DDIM
                                      + c * 32 + quad * 8;
                float4 xa = *(const float4*)xrow;
                float4 xb = *(const float4*)(xrow + 4);
                s += xa.x * xa.x + xa.y * xa.y + xa.z * xa.z + xa.w * xa.w;
                s += xb.x * xb.x + xb.y * xb.y + xb.z * xb.z + xb.w * xb.w;
                float f[8] = {xa.x, xa.y, xa.z, xa.w, xb.x, xb.y, xb.z, xb.w};
                union { bf16x8 v; unsigned short u[8]; } H, L;
                #pragma unroll
                for (int e = 0; e < 8; ++e) {
                    unsigned short h = f2bf_rne(f[e]);
                    H.u[e] = h;
                    L.u[e] = f2bf_rne(f[e] - bf2f(h));
                }
                xh[j][c] = H.v;
                xl[j][c] = L.v;
            }
            // sum partial ||x||^2 across the 4 quads (bits 4,5 of lane)
            s += __shfl_xor(s, 16);
            s += __shfl_xor(s, 32);
            xnorm[j] = s;
        }

        // ---- argmax of score = sim - 0.5*||e||^2 over 32 code-tiles ----
        float best[2], second[2];
        int bestv[2];  // t*16 + reg  (full code = bestv + quad*4)
        #pragma unroll
        for (int j = 0; j < 2; ++j) { best[j] = -3.4e38f; second[j] = -3.4e38f; bestv[j] = 0; }

        // prefetched fragments for tile t
        bf16x8 eh0 = ehv[lane], eh1 = ehv[64 + lane];
        bf16x8 el0 = elv[lane], el1 = elv[64 + lane];

        #pragma unroll 1
        for (int t = 0; t < 32; ++t) {
            // prefetch t+1 (wraps to t=0 on last iter; harmless, unused)
            const int tn = (t + 1) & 31;
            bf16x8 neh0 = ehv[(tn * 2 + 0) * 64 + lane];
            bf16x8 neh1 = ehv[(tn * 2 + 1) * 64 + lane];
            bf16x8 nel0 = elv[(tn * 2 + 0) * 64 + lane];
            bf16x8 nel1 = elv[(tn * 2 + 1) * 64 + lane];
            float4 cn = sh_cn[t * 4 + quad];
            const int kb = t * 16;
            #pragma unroll
            for (int j = 0; j < 2; ++j) {
                f32x4 acc = {cn.x, cn.y, cn.z, cn.w};   // start at -0.5*||e||^2
                acc = __builtin_amdgcn_mfma_f32_16x16x32_bf16(eh0, xh[j][0], acc, 0, 0, 0);
                acc = __builtin_amdgcn_mfma_f32_16x16x32_bf16(eh1, xh[j][1], acc, 0, 0, 0);
                acc = __builtin_amdgcn_mfma_f32_16x16x32_bf16(el0, xh[j][0], acc, 0, 0, 0);
                acc = __builtin_amdgcn_mfma_f32_16x16x32_bf16(el1, xh[j][1], acc, 0, 0, 0);
                acc = __builtin_amdgcn_mfma_f32_16x16x32_bf16(eh0, xl[j][0], acc, 0, 0, 0);
                acc = __builtin_amdgcn_mfma_f32_16x16x32_bf16(eh1, xl[j][1], acc, 0, 0, 0);
                #pragma unroll
                for (int r = 0; r < 4; ++r) {
                    float s = acc[r];
                    // new second = median(s, best, second) given best >= second
                    second[j] = __builtin_amdgcn_fmed3f(s, best[j], second[j]);
                    bool gt = s > best[j];
                    bestv[j] = gt ? (kb + r) : bestv[j];
                    best[j] = fmaxf(best[j], s);
                }
            }
            eh0 = neh0; eh1 = neh1; el0 = nel0; el1 = nel1;
        }

        // ---- reduce across the 4 quads (lanes n, n+16, n+32, n+48) ----
        int bk[2];
        #pragma unroll
        for (int j = 0; j < 2; ++j) bk[j] = bestv[j] + quad * 4;
        #pragma unroll
        for (int j = 0; j < 2; ++j) {
            #pragma unroll
            for (int m = 16; m <= 32; m <<= 1) {
                float ob = __shfl_xor(best[j], m);
                float os = __shfl_xor(second[j], m);
                int   ok = __shfl_xor(bk[j], m);
                float nb = fmaxf(best[j], ob);
                float ns = fmaxf(fmaxf(second[j], os), fminf(best[j], ob));
                bool take = (ob > best[j]) || (ob == best[j] && ok < bk[j]);
                bk[j] = take ? ok : bk[j];
                best[j] = nb;
                second[j] = ns;
            }
        }

        // ---- back to distance domain: dist = -2*score  (||x||^2 dropped) ----
        float bd[2], sd[2];
        #pragma unroll
        for (int j = 0; j < 2; ++j) { bd[j] = -2.f * best[j]; sd[j] = -2.f * second[j]; }

        // ---- near-tie: whole-wave cooperative exact fp64 rescan (rare) ----
        #pragma unroll
        for (int j = 0; j < 2; ++j) {
            unsigned long long need = __ballot(sd[j] - bd[j] < TIE_TH) & 0xFFFFULL;
            while (need) {
                int nl = __ffsll(need) - 1;
                need &= need - 1;
                const float* xr = x + (size_t)(nbase + j * 16 + nl) * DDIM;
                double dmin = 1e300;
                int kmin = 0;
                #pragma unroll
                for (int i = 0; i < 8; ++i) {
                    int k = lane * 8 + i;
                    const float* er = et + k * DDIM;
                    double s = 0.0;
                    for (int d4 = 0; d4 < 16; ++d4) {
                        float4 xv = *(const float4*)(xr + d4 * 4);
                        float4 ev = *(const float4*)(er + d4 * 4);
                        double a = (double)xv.x - (double)ev.x; s += a * a;
                        double b = (double)xv.y - (double)ev.y; s += b * b;
                        double c = (double)xv.z - (double)ev.z; s += c * c;
                        double e = (double)xv.w - (double)ev.w; s += e * e;
                    }
                    if (s < dmin) { dmin = s; kmin = k; }
                }
                #pragma unroll
                for (int m = 1; m < 64; m <<= 1) {
                    double od = __shfl_xor(dmin, m);
                    int   ok = __shfl_xor(kmin, m);
                    if (od < dmin || (od == dmin && ok < kmin)) { dmin = od; kmin = ok; }
                }
                if ((lane & 15) == nl) {
                    bk[j] = kmin;
                    bd[j] = (float)dmin - xnorm[j];  // keep loss exact
                }
            }
        }

        // ---- loss partial: sum (q-x)^2 = xnorm + bd over this wave's 32 n ----
        float ls = 0.f;
        if (lane < 16) {
            #pragma unroll
            for (int j = 0; j < 2; ++j) ls += fmaxf(xnorm[j] + bd[j], 0.f);
        }
        #pragma unroll
        for (int m = 1; m < 64; m <<= 1) ls += __shfl_xor(ls, m);
        loss_ws += ls;

        // ---- write quantized rows: lane -> (n = lane>>2, 64B slice = lane&3) ----
        #pragma unroll
        for (int j = 0; j < 2; ++j) {
            int bkn = __shfl(bk[j], lane >> 2);
            const float4* er = (const float4*)(et + (size_t)bkn * DDIM + (lane & 3) * 16);
            float4* op = (float4*)(out + (size_t)(nbase + j * 16 + (lane >> 2)) * DDIM
                                       + (lane & 3) * 16);
            op[0] = er[0]; op[1] = er[1]; op[2] = er[2]; op[3] = er[3];
        }
    }

    if (lane == 0) atomicAdd(loss_accum, loss_ws);
}

// ---------------- legacy fallback (round-1 kernel) if ws is too small ----------------
__global__ __launch_bounds__(256) void vq_main_legacy(const float* __restrict__ x,
                                                      const float* __restrict__ emb,
                                                      const float* __restrict__ wsf,
                                                      float* __restrict__ out,
                                                      float* __restrict__ loss_accum) {
    const int n = blockIdx.x * 256 + threadIdx.x;
    const float* __restrict__ cnorm = wsf + WS_CNORM;
    const float* __restrict__ et    = wsf + WS_ET;
    float xr[DDIM];
    {
        const float4* xp = (const float4*)(x + (size_t)n * DDIM);
        #pragma unroll
        for (int d4 = 0; d4 < DDIM / 4; ++d4) {
            float4 v = xp[d4];
            xr[4 * d4 + 0] = v.x; xr[4 * d4 + 1] = v.y;
            xr[4 * d4 + 2] = v.z; xr[4 * d4 + 3] = v.w;
        }
    }
    float best = 3.4e38f, second = 3.4e38f;
    int bestk = 0;
    for (int k0 = 0; k0 < KCB; k0 += 8) {
        float acc[8];
        #pragma unroll
        for (int j = 0; j < 8; ++j) acc[j] = 0.f;
        #pragma unroll
        for (int j = 0; j < 8; ++j) {
            const float* ek = et + (k0 + j) * DDIM;
            float s = 0.f;
            #pragma unroll
            for (int d = 0; d < DDIM; ++d) s += xr[d] * ek[d];
            acc[j] = s;
        }
        #pragma unroll
        for (int j = 0; j < 8; ++j) {
            float dist = cnorm[k0 + j] - 2.f * acc[j];
            if (dist < best) { second = best; best = dist; bestk = k0 + j; }
            else if (dist < second) { second = dist; }
        }
    }
    if (second - best < TIE_TH) {
        double bestd = 1e300;
        int bkk = 0;
        for (int k = 0; k < KCB; ++k) {
            const float* ek = et + k * DDIM;
            double s = 0.0;
            #pragma unroll
            for (int d = 0; d < DDIM; ++d) {
                double diff = (double)xr[d] - (double)ek[d];
                s += diff * diff;
            }
            if (s < bestd) { bestd = s; bkk = k; }
        }
        bestk = bkk;
    }
    float sq = 0.f;
    {
        const float4* qp = (const float4*)(et + bestk * DDIM);
        float4* op = (float4*)(out + (size_t)n * DDIM);
        #pragma unroll
        for (int d4 = 0; d4 < DDIM / 4; ++d4) {
            float4 q = qp[d4];
            op[d4] = q;
            float a = q.x - xr[4 * d4 + 0];
            float b = q.y - xr[4 * d4 + 1];
            float c = q.z - xr[4 * d4 + 2];
            float e = q.w - xr[4 * d4 + 3];
            sq += a * a + b * b + c * c + e * e;
        }
    }
    #pragma unroll
    for (int off = 32; off > 0; off >>= 1) sq += __shfl_down(sq, off);
    __shared__ float red[4];
    const int lane = threadIdx.x & 63;
    const int wid  = threadIdx.x >> 6;
    if (lane == 0) red[wid] = sq;
    __syncthreads();
    if (threadIdx.x == 0) atomicAdd(loss_accum, red[0] + red[1] + red[2] + red[3]);
}

__global__ void vq_final(const float* __restrict__ loss_accum,
                         float* __restrict__ out) {
    out[(size_t)NVEC * DDIM] = 1.25f * loss_accum[0] / 16777216.f;
}

extern "C" void kernel_launch(void* const* d_in, const int* in_sizes, int n_in,
                              void* d_out, int out_size, void* d_ws, size_t ws_size,
                              hipStream_t stream) {
    const float* x   = (const float*)d_in[0];
    const float* emb = (const float*)d_in[1];
    float* out = (float*)d_out;
    float* wsf = (float*)d_ws;

    vq_prep1<<<1, 512, 0, stream>>>(emb, wsf);
    if (ws_size >= (size_t)WS_END * 4) {
        vq_prep2<<<8, 512, 0, stream>>>(emb, wsf);
        vq_main_mfma<<<NVEC / 1024, 1024, 0, stream>>>(x, wsf, out, wsf + WS_LOSS);
    } else {
        vq_main_legacy<<<NVEC / 256, 256, 0, stream>>>(x, emb, wsf, out, wsf + WS_LOSS);
    }
    vq_final<<<1, 1, 0, stream>>>(wsf + WS_LOSS, out);
}